// Round 2
// baseline (374.397 us; speedup 1.0000x reference)
//
#include <hip/hip_runtime.h>

// DiscriminativeLoss — B=8, D=32, N from in_sizes, K=64 instance bins.
// Pass 1: per-cluster counts/sums (LDS accumulate, native-atomic flush).
// Pass 2: hinged L1 variance vs cluster means. Pass 3: tiny finalize.
// R1 change: native atomics (int counts, unsafeAtomicAdd for fp32) — the R0
// generic-pointer float atomicAdd lowered to a flat CAS loop (VALUBusy 0.67%,
// HBM 5%, 180us stall storm). Also 2x grid + register-prefetch of 8 rows.

#define IGNORE_IDX (-100)

constexpr int B = 8;
constexpr int D = 32;
constexpr int K = 64;
constexpr float DELTA_V = 0.5f;
constexpr float TWO_DELTA_D = 3.0f;   // 2 * DELTA_D
constexpr float PARAM_REG = 0.001f;

constexpr int BK  = B * K;            // 512
constexpr int BKD = B * K * D;        // 16384

// ws layout: [0,BK) int counts | floats: [BK, BK+BKD) sums | [BK+BKD, +BK) var_seg

// ---------------------------------------------------------------- K1: segment sums
__global__ __launch_bounds__(256) void k1_segsum(
    const float* __restrict__ x, const int* __restrict__ sem,
    const int* __restrict__ inst, int* __restrict__ g_counts,
    float* __restrict__ g_sums, int N, int blocksPerBatch)
{
    __shared__ float s_sums[K][D + 1];   // stride 33 -> bank (k+d)%32
    __shared__ int   s_counts[K];

    const int b     = blockIdx.x / blocksPerBatch;
    const int chunk = blockIdx.x - b * blocksPerBatch;
    const int t     = threadIdx.x;

    for (int i = t; i < K * (D + 1); i += 256) (&s_sums[0][0])[i] = 0.f;
    if (t < K) s_counts[t] = 0;
    __syncthreads();

    const int pts  = N / blocksPerBatch;          // 1024: one 4-pt group/thread
    const int base = chunk * pts + t * 4;
    const float* xb = x + (size_t)b * D * N;

    const int4 c4 = *(const int4*)(sem  + (size_t)b * N + base);
    const int4 i4 = *(const int4*)(inst + (size_t)b * N + base);
    const int cl[4] = {c4.x, c4.y, c4.z, c4.w};
    const int il[4] = {i4.x, i4.y, i4.z, i4.w};
    int  id[4];
    bool v[4];
#pragma unroll
    for (int j = 0; j < 4; ++j) {
        v[j]  = (cl[j] != IGNORE_IDX);
        int q = (cl[j] == 1) ? 0 : il[j];
        id[j] = (q < 0) ? 0 : (q > K - 1 ? K - 1 : q);
    }
#pragma unroll
    for (int j = 0; j < 4; ++j)
        if (v[j]) atomicAdd(&s_counts[id[j]], 1);

#pragma unroll
    for (int dc = 0; dc < 4; ++dc) {
        float4 xv[8];                              // prefetch 8 rows -> batch vmcnt
#pragma unroll
        for (int dd = 0; dd < 8; ++dd)
            xv[dd] = *(const float4*)(xb + (size_t)(dc * 8 + dd) * N + base);
#pragma unroll
        for (int dd = 0; dd < 8; ++dd) {
            const int d = dc * 8 + dd;
            if (v[0]) unsafeAtomicAdd(&s_sums[id[0]][d], xv[dd].x);
            if (v[1]) unsafeAtomicAdd(&s_sums[id[1]][d], xv[dd].y);
            if (v[2]) unsafeAtomicAdd(&s_sums[id[2]][d], xv[dd].z);
            if (v[3]) unsafeAtomicAdd(&s_sums[id[3]][d], xv[dd].w);
        }
    }
    __syncthreads();

    for (int i = t; i < K * D; i += 256) {
        const float s = s_sums[i >> 5][i & 31];
        if (s != 0.f) unsafeAtomicAdd(&g_sums[b * K * D + i], s);
    }
    if (t < K) {
        const int c = s_counts[t];
        if (c) atomicAdd(&g_counts[b * K + t], c);
    }
}

// ---------------------------------------------------------------- K3: variance pass
__global__ __launch_bounds__(256) void k3_var(
    const float* __restrict__ x, const int* __restrict__ sem,
    const int* __restrict__ inst, const int* __restrict__ g_counts,
    const float* __restrict__ g_sums, float* __restrict__ g_var,
    int N, int blocksPerBatch)
{
    __shared__ float s_mu[K][D + 1];
    __shared__ float s_var[K];

    const int b     = blockIdx.x / blocksPerBatch;
    const int chunk = blockIdx.x - b * blocksPerBatch;
    const int t     = threadIdx.x;

    for (int i = t; i < K * D; i += 256) {
        const int k = i >> 5, d = i & 31;
        s_mu[k][d] = g_sums[b * K * D + i] / ((float)g_counts[b * K + k] + 1e-8f);
    }
    if (t < K) s_var[t] = 0.f;
    __syncthreads();

    const int pts  = N / blocksPerBatch;
    const int base = chunk * pts + t * 4;
    const float* xb = x + (size_t)b * D * N;

    const int4 c4 = *(const int4*)(sem  + (size_t)b * N + base);
    const int4 i4 = *(const int4*)(inst + (size_t)b * N + base);
    const int cl[4] = {c4.x, c4.y, c4.z, c4.w};
    const int il[4] = {i4.x, i4.y, i4.z, i4.w};
    int  id[4];
    bool v[4];
#pragma unroll
    for (int j = 0; j < 4; ++j) {
        v[j]  = (cl[j] != IGNORE_IDX);
        int q = (cl[j] == 1) ? 0 : il[j];
        id[j] = (q < 0) ? 0 : (q > K - 1 ? K - 1 : q);
    }

    float dist[4] = {0.f, 0.f, 0.f, 0.f};
#pragma unroll
    for (int dc = 0; dc < 4; ++dc) {
        float4 xv[8];
#pragma unroll
        for (int dd = 0; dd < 8; ++dd)
            xv[dd] = *(const float4*)(xb + (size_t)(dc * 8 + dd) * N + base);
#pragma unroll
        for (int dd = 0; dd < 8; ++dd) {
            const int d = dc * 8 + dd;
            dist[0] += fabsf(xv[dd].x - s_mu[id[0]][d]);
            dist[1] += fabsf(xv[dd].y - s_mu[id[1]][d]);
            dist[2] += fabsf(xv[dd].z - s_mu[id[2]][d]);
            dist[3] += fabsf(xv[dd].w - s_mu[id[3]][d]);
        }
    }
#pragma unroll
    for (int j = 0; j < 4; ++j) {
        if (v[j]) {
            const float h = fmaxf(dist[j] - DELTA_V, 0.f);
            if (h > 0.f) unsafeAtomicAdd(&s_var[id[j]], h * h);
        }
    }
    __syncthreads();

    if (t < K) {
        const float s = s_var[t];
        if (s != 0.f) unsafeAtomicAdd(&g_var[b * K + t], s);
    }
}

// ---------------------------------------------------------------- K4: per-batch finalize
__device__ float block_reduce_sum(float v, float* s_buf) {
    for (int o = 32; o > 0; o >>= 1) v += __shfl_down(v, o, 64);
    const int wid  = threadIdx.x >> 6;
    const int lane = threadIdx.x & 63;
    if (lane == 0) s_buf[wid] = v;
    __syncthreads();
    float r = 0.f;
    if (threadIdx.x == 0)
        for (int w = 0; w < 8; ++w) r += s_buf[w];
    __syncthreads();
    return r;   // valid on thread 0 only
}

__global__ __launch_bounds__(512) void k4_final(const int* __restrict__ g_counts_all,
                                                const float* __restrict__ g_sums_all,
                                                const float* __restrict__ g_var_all,
                                                float* __restrict__ out)
{
    const int b = blockIdx.x;
    const int*   g_counts = g_counts_all + b * K;
    const float* g_sums   = g_sums_all + (size_t)b * K * D;
    const float* g_var    = g_var_all + b * K;

    __shared__ float s_mu[K][D + 1];
    __shared__ float s_cnt[K];
    __shared__ float s_present[K];
    __shared__ float s_red[8];

    const int t = threadIdx.x;
    for (int i = t; i < K; i += 512) {
        const float c = (float)g_counts[i];
        s_cnt[i]     = c;
        s_present[i] = (c > 0.f) ? 1.f : 0.f;
    }
    __syncthreads();
    for (int i = t; i < K * D; i += 512) {
        const int k = i >> 5, d = i & 31;
        s_mu[k][d] = g_sums[i] / (s_cnt[k] + 1e-8f);
    }
    __syncthreads();

    float distPart = 0.f;
    for (int p = t; p < K * K; p += 512) {
        const int i = p >> 6, j = p & 63;
        if (i != j && s_present[i] > 0.f && s_present[j] > 0.f) {
            float dsum = 0.f;
#pragma unroll
            for (int d = 0; d < D; ++d) dsum += fabsf(s_mu[i][d] - s_mu[j][d]);
            const float h = fmaxf(TWO_DELTA_D - dsum, 0.f);
            distPart += h * h;
        }
    }
    float regPart = 0.f;
    for (int i = t; i < K * D; i += 512) {
        const int k = i >> 5;
        if (s_present[k] > 0.f) regPart += fabsf(s_mu[k][i & 31]);
    }
    float varPart = 0.f;
    for (int k = t; k < K; k += 512) varPart += g_var[k] / (s_cnt[k] + 1e-8f);
    float npPart = 0.f;
    for (int k = t; k < K; k += 512) npPart += s_present[k];

    const float distSum = block_reduce_sum(distPart, s_red);
    const float regSum  = block_reduce_sum(regPart,  s_red);
    const float varSum  = block_reduce_sum(varPart,  s_red);
    const float npSum   = block_reduce_sum(npPart,   s_red);

    if (t == 0) {
        const float n_inst = fmaxf(npSum, 1.0f);
        const float npairs = npSum * npSum - npSum;   // ordered present pairs
        const float l_var  = varSum / n_inst;
        const float l_dist = (npairs > 0.f) ? (distSum / fmaxf(npairs, 1.0f)) : 0.f;
        const float l_reg  = PARAM_REG * (regSum / n_inst);
        const float loss   = l_var + l_dist + l_reg;
        const float invB   = 1.0f / (float)B;
        unsafeAtomicAdd(out + 0, loss   * invB);
        unsafeAtomicAdd(out + 1, l_var  * invB);
        unsafeAtomicAdd(out + 2, l_dist * invB);
        unsafeAtomicAdd(out + 3, l_reg  * invB);
    }
}

// ---------------------------------------------------------------- launch
extern "C" void kernel_launch(void* const* d_in, const int* in_sizes, int n_in,
                              void* d_out, int out_size, void* d_ws, size_t ws_size,
                              hipStream_t stream) {
    const float* x    = (const float*)d_in[0];
    const int*   sem  = (const int*)d_in[1];
    const int*   inst = (const int*)d_in[2];
    float*       out  = (float*)d_out;

    int*   g_counts = (int*)d_ws;
    float* g_sums   = (float*)d_ws + BK;
    float* g_var    = (float*)d_ws + BK + BKD;

    const int N = in_sizes[1] / B;
    const int blocksPerBatch = N / 1024;   // 256 thr x 4 pts each

    hipMemsetAsync(d_ws, 0, (size_t)(BK + BKD + BK) * sizeof(float), stream);
    hipMemsetAsync(out, 0, (size_t)out_size * sizeof(float), stream);

    k1_segsum<<<dim3(B * blocksPerBatch), dim3(256), 0, stream>>>(
        x, sem, inst, g_counts, g_sums, N, blocksPerBatch);
    k3_var<<<dim3(B * blocksPerBatch), dim3(256), 0, stream>>>(
        x, sem, inst, g_counts, g_sums, g_var, N, blocksPerBatch);
    k4_final<<<dim3(B), dim3(512), 0, stream>>>(g_counts, g_sums, g_var, out);
}